// Round 5
// baseline (245.662 us; speedup 1.0000x reference)
//
#include <hip/hip_runtime.h>

#define GRID_D 64
#define NN (GRID_D * GRID_D)   // 4096 nodes per image
#define H 64
#define C_IN 12
#define B_SZ 128
#define LN_EPS 1e-5f

typedef __bf16 bf16x8 __attribute__((ext_vector_type(8)));
typedef float  f32x4  __attribute__((ext_vector_type(4)));

#define AS1 __attribute__((address_space(1)))
#define AS3 __attribute__((address_space(3)))

__device__ __forceinline__ float b2f_lo(unsigned u) {
    union { unsigned x; float f; } c; c.x = u << 16; return c.f;
}
__device__ __forceinline__ float b2f_hi(unsigned u) {
    union { unsigned x; float f; } c; c.x = u & 0xffff0000u; return c.f;
}

// mean of 4 neighbor fragments (bf16x8 each), word-wise unpack
__device__ __forceinline__ bf16x8 agg4(bf16x8 a, bf16x8 b, bf16x8 c, bf16x8 d, float inv) {
    union U { bf16x8 v; unsigned w[4]; };
    U A, Bv, Cv, Dv, O;
    A.v = a; Bv.v = b; Cv.v = c; Dv.v = d;
    #pragma unroll
    for (int i = 0; i < 4; ++i) {
        float lo = (b2f_lo(A.w[i]) + b2f_lo(Bv.w[i]) + b2f_lo(Cv.w[i]) + b2f_lo(Dv.w[i])) * inv;
        float hi = (b2f_hi(A.w[i]) + b2f_hi(Bv.w[i]) + b2f_hi(Cv.w[i]) + b2f_hi(Dv.w[i])) * inv;
        O.v[2 * i]     = (__bf16)lo;
        O.v[2 * i + 1] = (__bf16)hi;
    }
    return O.v;
}

// swizzled LDS tile address: tile st[6 rows][64 cols][64 feats], 16B slot XOR-swizzled
__device__ __forceinline__ const __bf16* sta(const __bf16* st, int rr, int c, int c8) {
    return st + ((rr * 64 + c) << 6) + ((c8 ^ (c & 7)) << 3);
}

// ---------------------------------------------------------------------------
// Kernel 0: weight prep — wt[l][g][j][k] = W[l,g][k][j]  (transposed, bf16)
// ---------------------------------------------------------------------------
__global__ __launch_bounds__(256) void k_prep(
    const float* __restrict__ ws_, const float* __restrict__ wn_,
    __bf16* __restrict__ wt)
{
    int i = blockIdx.x * 256 + threadIdx.x;      // 0..24575
    if (i < 3 * 2 * 4096) {
        int l = i >> 13;
        int g = (i >> 12) & 1;
        int j = (i >> 6) & 63;
        int k = i & 63;
        const float* W = (g ? wn_ : ws_) + l * 4096;
        wt[i] = (__bf16)W[k * 64 + j];
    }
}

// ---------------------------------------------------------------------------
// Kernel 1: input projection  h[b,n,j] = sum_c x[b,c,n] * w_in[c,j] + b_in[j]
// ---------------------------------------------------------------------------
__global__ __launch_bounds__(256) void k_inproj(
    const float* __restrict__ x, const float* __restrict__ w_in,
    const float* __restrict__ b_in, __bf16* __restrict__ h)
{
    int bid = blockIdx.x;            // b*64 + r
    int b = bid >> 6, r = bid & 63;
    __shared__ float xs[C_IN][GRID_D];
    __shared__ float ws[C_IN][H];
    int tid = threadIdx.x;
    const float* xb = x + (size_t)b * C_IN * NN + (size_t)r * GRID_D;
    for (int idx = tid; idx < C_IN * GRID_D; idx += 256) {
        int c = idx >> 6, n = idx & 63;
        xs[c][n] = xb[(size_t)c * NN + n];
        ws[c][n] = w_in[idx];
    }
    __syncthreads();
    int j = tid & 63;
    int g = tid >> 6;
    float bj = b_in[j];
    __bf16* hp = h + (size_t)(b * NN + r * GRID_D) * H;
    for (int n = g * 16; n < g * 16 + 16; ++n) {
        float acc = bj;
        #pragma unroll
        for (int c = 0; c < C_IN; ++c) acc += xs[c][n] * ws[c][j];
        hp[n * H + j] = (__bf16)acc;
    }
}

// ---------------------------------------------------------------------------
// Kernel 2: one SAGE layer + LayerNorm + residual ReLU.
// Block = 512 threads (8 waves) = 4 full grid rows (256 nodes) of one image.
// Tile (4 rows + 1 halo row each side, full 64-col width) staged to LDS via
// global_load_lds with pre-swizzled source (rule 21); OOB halo rows stream
// from a zeroed scratch buffer. Col edges handled by exec-masked L/R reads.
// Weights read as B-frags straight from pre-transposed bf16 global buffer.
// 48KB static LDS -> 3 blocks/CU. LAST fuses the head.
// ---------------------------------------------------------------------------
template <bool LAST>
__global__ __launch_bounds__(512, 6) void k_layer(
    const __bf16* __restrict__ h_in, __bf16* __restrict__ h_out,
    float* __restrict__ logits,
    const __bf16* __restrict__ wt_l,       // [2][64 j][64 k] transposed bf16
    const __bf16* __restrict__ zbuf,       // >=1KB of zeros
    const float* __restrict__ cb, const float* __restrict__ lg,
    const float* __restrict__ lb,
    const float* __restrict__ w_head, const float* __restrict__ b_head)
{
    __shared__ __bf16 st[6 * 64 * 64];     // 48 KB

    int tid = threadIdx.x;
    int bid = blockIdx.x;                  // img*16 + tile
    int img = bid >> 4, tile = bid & 15;
    int r0 = tile * 4;
    const __bf16* hb = h_in + (size_t)img * NN * H;
    __bf16*       ho = h_out + (size_t)img * NN * H;
    int nb = r0 * GRID_D;

    int ln = tid & 63, wv = tid >> 6;

    // ---- stage tile: 48 chunks of 8 nodes (1KB each), 6 per wave ----
    int lnode = ln >> 3;                           // node within chunk 0..7
    int lslot = ((ln & 7) ^ lnode) << 3;           // pre-swizzled c8 slot (elems)
    #pragma unroll
    for (int i = 0; i < 6; ++i) {
        int q = i * 8 + wv;
        int rr = q >> 3, cc0 = (q & 7) * 8;
        int grow = r0 - 1 + rr;
        const __bf16* src;
        if (grow >= 0 && grow < GRID_D)
            src = hb + (((size_t)(grow * GRID_D + cc0 + lnode)) << 6) + lslot;
        else
            src = zbuf + (lnode << 6) + lslot;     // zero halo row
        __bf16* dst = st + ((size_t)(rr * 64 + cc0) << 6);   // wave-uniform, linear
        __builtin_amdgcn_global_load_lds((const AS1 void*)src, (AS3 void*)dst, 16, 0, 0);
    }
    __syncthreads();   // drains vmcnt before any wave reads the tile

    // ---- GEMM setup ----
    int lrow = ln & 15, kgrp = ln >> 4;
    int lr = wv >> 1;                     // wave's local grid row 0..3
    int cbase = (wv & 1) * 32;
    int col0 = cbase + lrow;              // a0 column (0..47)
    int col1 = cbase + 16 + lrow;         // a1 column (16..63)
    int growc = r0 + lr;
    float inv0 = 1.0f / (float)((growc > 0) + (growc < 63) + (col0 > 0) + 1);
    float inv1 = 1.0f / (float)((growc > 0) + (growc < 63) + 1 + (col1 < 63));

    const __bf16* wts = wt_l;             // Ws^T
    const __bf16* wtn = wt_l + 4096;      // Wn^T

    f32x4 acc[2][4];
    #pragma unroll
    for (int nt = 0; nt < 2; ++nt)
        #pragma unroll
        for (int ft = 0; ft < 4; ++ft) acc[nt][ft] = (f32x4){0.f, 0.f, 0.f, 0.f};

    // ---- phase 1: self @ Ws ----
    #pragma unroll
    for (int ks = 0; ks < 2; ++ks) {
        int c8 = ks * 4 + kgrp, k0 = c8 << 3;
        bf16x8 a0 = *(const bf16x8*)sta(st, 1 + lr, col0, c8);
        bf16x8 a1 = *(const bf16x8*)sta(st, 1 + lr, col1, c8);
        #pragma unroll
        for (int ft = 0; ft < 4; ++ft) {
            bf16x8 bfrag = *(const bf16x8*)&wts[((ft * 16 + lrow) << 6) + k0];
            acc[0][ft] = __builtin_amdgcn_mfma_f32_16x16x32_bf16(a0, bfrag, acc[0][ft], 0, 0, 0);
            acc[1][ft] = __builtin_amdgcn_mfma_f32_16x16x32_bf16(a1, bfrag, acc[1][ft], 0, 0, 0);
        }
    }

    // ---- phase 2: agg @ Wn (A-frags built on the fly from tile) ----
    #pragma unroll
    for (int ks = 0; ks < 2; ++ks) {
        int c8 = ks * 4 + kgrp, k0 = c8 << 3;
        bf16x8 z = {};
        bf16x8 u0 = *(const bf16x8*)sta(st, lr,     col0, c8);
        bf16x8 d0 = *(const bf16x8*)sta(st, lr + 2, col0, c8);
        bf16x8 l0 = z;
        if (col0 > 0) l0 = *(const bf16x8*)sta(st, lr + 1, col0 - 1, c8);
        bf16x8 rv0 = *(const bf16x8*)sta(st, lr + 1, col0 + 1, c8);   // col0+1 <= 48
        bf16x8 g0 = agg4(l0, rv0, u0, d0, inv0);

        bf16x8 u1 = *(const bf16x8*)sta(st, lr,     col1, c8);
        bf16x8 d1 = *(const bf16x8*)sta(st, lr + 2, col1, c8);
        bf16x8 l1 = *(const bf16x8*)sta(st, lr + 1, col1 - 1, c8);    // col1-1 >= 15
        bf16x8 rv1 = z;
        if (col1 < 63) rv1 = *(const bf16x8*)sta(st, lr + 1, col1 + 1, c8);
        bf16x8 g1 = agg4(l1, rv1, u1, d1, inv1);

        #pragma unroll
        for (int ft = 0; ft < 4; ++ft) {
            bf16x8 bfrag = *(const bf16x8*)&wtn[((ft * 16 + lrow) << 6) + k0];
            acc[0][ft] = __builtin_amdgcn_mfma_f32_16x16x32_bf16(g0, bfrag, acc[0][ft], 0, 0, 0);
            acc[1][ft] = __builtin_amdgcn_mfma_f32_16x16x32_bf16(g1, bfrag, acc[1][ft], 0, 0, 0);
        }
    }

    // ---- epilogue: +bias, LN over 64 feats, residual (from LDS) + ReLU ----
    float cbv[4], lgv[4], lbv[4], whv[4];
    #pragma unroll
    for (int ft = 0; ft < 4; ++ft) {
        int j = ft * 16 + lrow;
        cbv[ft] = cb[j]; lgv[ft] = lg[j]; lbv[ft] = lb[j];
        if (LAST) whv[ft] = w_head[j];
    }
    float bh = LAST ? b_head[0] : 0.f;

    #pragma unroll
    for (int nt = 0; nt < 2; ++nt) {
        #pragma unroll
        for (int t = 0; t < 4; ++t) {
            int nl   = wv * 32 + nt * 16 + 4 * kgrp + t;   // block-local node
            int colc = cbase + nt * 16 + 4 * kgrp + t;     // its grid column
            float v[4], s1v = 0.f, s2v = 0.f;
            #pragma unroll
            for (int ft = 0; ft < 4; ++ft) {
                float xv = acc[nt][ft][t] + cbv[ft];
                v[ft] = xv; s1v += xv; s2v += xv * xv;
            }
            #pragma unroll
            for (int m = 1; m < 16; m <<= 1) {
                s1v += __shfl_xor(s1v, m);
                s2v += __shfl_xor(s2v, m);
            }
            float mu   = s1v * (1.0f / H);
            float var  = s2v * (1.0f / H) - mu * mu;
            float rstd = rsqrtf(var + LN_EPS);
            const __bf16* res = st + (((1 + lr) * 64 + colc) << 6);
            int cswz = colc & 7;
            if (LAST) {
                float part = 0.f;
                #pragma unroll
                for (int ft = 0; ft < 4; ++ft) {
                    int j = ft * 16 + lrow;
                    float sv = (float)res[(((j >> 3) ^ cswz) << 3) + (j & 7)];
                    float o  = sv + fmaxf((v[ft] - mu) * rstd * lgv[ft] + lbv[ft], 0.f);
                    part += o * whv[ft];
                }
                #pragma unroll
                for (int m = 1; m < 16; m <<= 1) part += __shfl_xor(part, m);
                if (lrow == 0) logits[(size_t)img * NN + nb + nl] = part + bh;
            } else {
                #pragma unroll
                for (int ft = 0; ft < 4; ++ft) {
                    int j = ft * 16 + lrow;
                    float sv = (float)res[(((j >> 3) ^ cswz) << 3) + (j & 7)];
                    float o  = sv + fmaxf((v[ft] - mu) * rstd * lgv[ft] + lbv[ft], 0.f);
                    ho[(size_t)(nb + nl) * H + j] = (__bf16)o;
                }
            }
        }
    }
}

// ---------------------------------------------------------------------------
extern "C" void kernel_launch(void* const* d_in, const int* in_sizes, int n_in,
                              void* d_out, int out_size, void* d_ws, size_t ws_size,
                              hipStream_t stream) {
    const float* x      = (const float*)d_in[0];
    // d_in[1] edge_index: fixed grid 4-neighborhood -> computed as stencil, unused
    const float* w_in   = (const float*)d_in[2];
    const float* b_in   = (const float*)d_in[3];
    const float* w_self = (const float*)d_in[4];
    const float* w_neigh= (const float*)d_in[5];
    const float* conv_b = (const float*)d_in[6];
    const float* ln_g   = (const float*)d_in[7];
    const float* ln_b   = (const float*)d_in[8];
    const float* w_head = (const float*)d_in[9];
    const float* b_head = (const float*)d_in[10];
    float* out = (float*)d_out;

    char* base = (char*)d_ws;
    const size_t HBYTES = (size_t)B_SZ * NN * H * sizeof(__bf16);   // 64 MiB
    __bf16* h_a  = (__bf16*)base;
    __bf16* h_b  = (__bf16*)(base + HBYTES);
    __bf16* wtb  = (__bf16*)(base + 2 * HBYTES);                    // 48 KiB
    __bf16* zbuf = (__bf16*)(base + 2 * HBYTES + 65536);            // 4 KiB zeros

    hipMemsetAsync(zbuf, 0, 4096, stream);
    k_prep<<<96, 256, 0, stream>>>(w_self, w_neigh, wtb);
    k_inproj<<<B_SZ * GRID_D, 256, 0, stream>>>(x, w_in, b_in, h_a);

    k_layer<false><<<B_SZ * 16, 512, 0, stream>>>(
        h_a, h_b, out, wtb,            zbuf, conv_b,         ln_g,         ln_b,         w_head, b_head);
    k_layer<false><<<B_SZ * 16, 512, 0, stream>>>(
        h_b, h_a, out, wtb + 8192,     zbuf, conv_b + H,     ln_g + H,     ln_b + H,     w_head, b_head);
    k_layer<true><<<B_SZ * 16, 512, 0, stream>>>(
        h_a, h_b, out, wtb + 16384,    zbuf, conv_b + 2 * H, ln_g + 2 * H, ln_b + 2 * H, w_head, b_head);
}

// Round 6
// 171.118 us; speedup vs baseline: 1.4356x; 1.4356x over previous
//
#include <hip/hip_runtime.h>

#define GRID_D 64
#define NN (GRID_D * GRID_D)   // 4096 nodes per image
#define H 64
#define C_IN 12
#define B_SZ 128
#define LN_EPS 1e-5f

typedef _Float16 f16x8 __attribute__((ext_vector_type(8)));
typedef float    f32x4 __attribute__((ext_vector_type(4)));

#define AS1 __attribute__((address_space(1)))
#define AS3 __attribute__((address_space(3)))

// masked global halo-row read (grow is wave-uniform; OOB -> zero)
__device__ __forceinline__ f16x8 gload_row(const _Float16* hb, int grow, int col, int k0) {
    if ((unsigned)grow < (unsigned)GRID_D)
        return *(const f16x8*)(hb + (((size_t)(grow * GRID_D + col)) << 6) + k0);
    return (f16x8){};
}

// ---------------------------------------------------------------------------
// Kernel 0: weight prep — pre-swizzled transposed f16 copies of Ws/Wn.
// Layout: wt[l][g][j][slot][e] where slot = (k>>3)^(j&7), e = k&7, value W[k][j].
// This makes k_layer's LDS staging a LINEAR copy (global_load_lds) while LDS
// reads use the XOR-swizzled addressing (conflict-free, measured R5).
// ---------------------------------------------------------------------------
__global__ __launch_bounds__(256) void k_prep(
    const float* __restrict__ ws_, const float* __restrict__ wn_,
    _Float16* __restrict__ wt)
{
    int i = blockIdx.x * 256 + threadIdx.x;      // 0..24575
    if (i < 3 * 2 * 4096) {
        int l = i >> 13, g = (i >> 12) & 1, j = (i >> 6) & 63, k = i & 63;
        const float* W = (g ? wn_ : ws_) + l * 4096;
        int dst = (((l * 2 + g) * 64 + j) << 6) + ((((k >> 3) ^ (j & 7)) << 3) | (k & 7));
        wt[dst] = (_Float16)W[k * 64 + j];
    }
}

// ---------------------------------------------------------------------------
// Kernel 1: input projection  h[b,n,j] = sum_c x[b,c,n] * w_in[c,j] + b_in[j]
// ---------------------------------------------------------------------------
__global__ __launch_bounds__(256) void k_inproj(
    const float* __restrict__ x, const float* __restrict__ w_in,
    const float* __restrict__ b_in, _Float16* __restrict__ h)
{
    int bid = blockIdx.x;            // b*64 + r
    int b = bid >> 6, r = bid & 63;
    __shared__ float xs[C_IN][GRID_D];
    __shared__ float ws[C_IN][H];
    int tid = threadIdx.x;
    const float* xb = x + (size_t)b * C_IN * NN + (size_t)r * GRID_D;
    for (int idx = tid; idx < C_IN * GRID_D; idx += 256) {
        int c = idx >> 6, n = idx & 63;
        xs[c][n] = xb[(size_t)c * NN + n];
        ws[c][n] = w_in[idx];
    }
    __syncthreads();
    int j = tid & 63;
    int g = tid >> 6;
    float bj = b_in[j];
    _Float16* hp = h + (size_t)(b * NN + r * GRID_D) * H;
    for (int n = g * 16; n < g * 16 + 16; ++n) {
        float acc = bj;
        #pragma unroll
        for (int c = 0; c < C_IN; ++c) acc += xs[c][n] * ws[c][j];
        hp[n * H + j] = (_Float16)acc;
    }
}

// ---------------------------------------------------------------------------
// Kernel 2: one SAGE layer + LayerNorm + residual ReLU (f16 state, MFMA).
// Block = 512 threads (8 waves) = 4 full grid rows (256 nodes) of one image.
// LDS: 32KB tile (4 compute rows, XOR-swizzled via pre-swizzled global src)
//    + 16KB weights (pre-swizzled by k_prep, staged linearly).
// 48KB total -> 3 blocks/CU (24 waves). Halo rows read from global in
// phase 2 (read-once data, no staging — only edge waves touch it).
// LAST fuses the head.
// ---------------------------------------------------------------------------
template <bool LAST>
__global__ __launch_bounds__(512, 6) void k_layer(
    const _Float16* __restrict__ h_in, _Float16* __restrict__ h_out,
    float* __restrict__ logits,
    const _Float16* __restrict__ wtb,      // this layer's [2][64][64] pre-swizzled
    const float* __restrict__ cb, const float* __restrict__ lg,
    const float* __restrict__ lb,
    const float* __restrict__ w_head, const float* __restrict__ b_head)
{
    __shared__ _Float16 st[4 * 64 * 64];   // 32 KB tile
    __shared__ _Float16 wl[2 * 64 * 64];   // 16 KB weights

    int tid = threadIdx.x;
    int bid = blockIdx.x;                  // img*16 + tile
    int img = bid >> 4, tile = bid & 15;
    int r0 = tile * 4;
    const _Float16* hb = h_in + (size_t)img * NN * H;
    _Float16*       ho = h_out + (size_t)img * NN * H;
    int nb = r0 * GRID_D;

    int ln = tid & 63, wv = tid >> 6;
    int lnode = ln >> 3;                         // node within 8-node chunk
    int lslot = ((ln & 7) ^ lnode) << 3;         // pre-swizzled feat slot (elems)

    // ---- stage tile: rows r0..r0+3, 32 chunks of 1KB, 4 per wave ----
    #pragma unroll
    for (int i = 0; i < 4; ++i) {
        int q = i * 8 + wv;                      // 0..31
        int rr = q >> 3, cc0 = (q & 7) * 8;
        const _Float16* src = hb + (((size_t)((r0 + rr) * GRID_D + cc0 + lnode)) << 6) + lslot;
        _Float16* dst = st + ((size_t)(rr * 64 + cc0) << 6);
        __builtin_amdgcn_global_load_lds((const AS1 void*)src, (AS3 void*)dst, 16, 0, 0);
    }
    // ---- stage weights: 16 chunks of 1KB, linear both sides ----
    #pragma unroll
    for (int i = 0; i < 2; ++i) {
        int c = i * 8 + wv;                      // 0..15
        const _Float16* src = wtb + c * 512 + ln * 8;
        _Float16* dst = wl + c * 512;
        __builtin_amdgcn_global_load_lds((const AS1 void*)src, (AS3 void*)dst, 16, 0, 0);
    }
    __syncthreads();   // compiler drains vmcnt before barrier

    // ---- GEMM setup ----
    int lrow = ln & 15, kgrp = ln >> 4;
    int lr = wv >> 1;                     // wave's tile-local row 0..3
    int cbase = (wv & 1) * 32;
    int col0 = cbase + lrow;              // a0 column (0..47)
    int col1 = cbase + 16 + lrow;         // a1 column (16..63)
    int growc = r0 + lr;                  // global grid row

    f32x4 acc[2][4];
    #pragma unroll
    for (int nt = 0; nt < 2; ++nt)
        #pragma unroll
        for (int ft = 0; ft < 4; ++ft) acc[nt][ft] = (f32x4){0.f, 0.f, 0.f, 0.f};

    // ---- phase 1: self @ Ws ----
    #pragma unroll
    for (int ks = 0; ks < 2; ++ks) {
        int c8 = ks * 4 + kgrp;
        int sl = (c8 ^ (lrow & 7)) << 3;         // col0&7 == col1&7 == lrow&7
        f16x8 a0 = *(const f16x8*)(st + ((lr * 64 + col0) << 6) + sl);
        f16x8 a1 = *(const f16x8*)(st + ((lr * 64 + col1) << 6) + sl);
        #pragma unroll
        for (int ft = 0; ft < 4; ++ft) {
            int j = ft * 16 + lrow;
            f16x8 bf = *(const f16x8*)(wl + (j << 6) + sl);
            acc[0][ft] = __builtin_amdgcn_mfma_f32_16x16x32_f16(a0, bf, acc[0][ft], 0, 0, 0);
            acc[1][ft] = __builtin_amdgcn_mfma_f32_16x16x32_f16(a1, bf, acc[1][ft], 0, 0, 0);
        }
    }

    // ---- phase 2: agg @ Wn (neighbor mean built with packed f16 adds) ----
    _Float16 inv0 = (_Float16)(1.0f / (float)((growc > 0) + (growc < 63) + (col0 > 0) + 1));
    _Float16 inv1 = (_Float16)(1.0f / (float)((growc > 0) + (growc < 63) + 1 + (col1 < 63)));
    #pragma unroll
    for (int ks = 0; ks < 2; ++ks) {
        int c8 = ks * 4 + kgrp;
        int sl = (c8 ^ (lrow & 7)) << 3;
        int k0 = ks * 32 + kgrp * 8;
        f16x8 z = {};

        // --- col tile 0 ---
        f16x8 u0 = (lr > 0) ? *(const f16x8*)(st + (((lr - 1) * 64 + col0) << 6) + sl)
                            : gload_row(hb, r0 - 1, col0, k0);
        f16x8 d0 = (lr < 3) ? *(const f16x8*)(st + (((lr + 1) * 64 + col0) << 6) + sl)
                            : gload_row(hb, r0 + 4, col0, k0);
        int cm0 = col0 - (col0 > 0);
        f16x8 l0 = *(const f16x8*)(st + ((lr * 64 + cm0) << 6) + ((c8 ^ (cm0 & 7)) << 3));
        if (col0 == 0) l0 = z;
        int cp0 = col0 + 1;                                   // <= 48, always in tile
        f16x8 r0v = *(const f16x8*)(st + ((lr * 64 + cp0) << 6) + ((c8 ^ (cp0 & 7)) << 3));
        f16x8 s0 = (l0 + r0v) + (u0 + d0);
        f16x8 g0;
        #pragma unroll
        for (int e = 0; e < 8; ++e) g0[e] = s0[e] * inv0;

        // --- col tile 1 ---
        f16x8 u1 = (lr > 0) ? *(const f16x8*)(st + (((lr - 1) * 64 + col1) << 6) + sl)
                            : gload_row(hb, r0 - 1, col1, k0);
        f16x8 d1 = (lr < 3) ? *(const f16x8*)(st + (((lr + 1) * 64 + col1) << 6) + sl)
                            : gload_row(hb, r0 + 4, col1, k0);
        int cm1 = col1 - 1;                                   // >= 15, always in tile
        f16x8 l1 = *(const f16x8*)(st + ((lr * 64 + cm1) << 6) + ((c8 ^ (cm1 & 7)) << 3));
        int cp1 = col1 + (col1 < 63);
        f16x8 r1v = *(const f16x8*)(st + ((lr * 64 + cp1) << 6) + ((c8 ^ (cp1 & 7)) << 3));
        if (col1 == 63) r1v = z;
        f16x8 s1 = (l1 + r1v) + (u1 + d1);
        f16x8 g1;
        #pragma unroll
        for (int e = 0; e < 8; ++e) g1[e] = s1[e] * inv1;

        #pragma unroll
        for (int ft = 0; ft < 4; ++ft) {
            int j = ft * 16 + lrow;
            f16x8 bf = *(const f16x8*)(wl + ((64 + j) << 6) + sl);
            acc[0][ft] = __builtin_amdgcn_mfma_f32_16x16x32_f16(g0, bf, acc[0][ft], 0, 0, 0);
            acc[1][ft] = __builtin_amdgcn_mfma_f32_16x16x32_f16(g1, bf, acc[1][ft], 0, 0, 0);
        }
    }

    // ---- epilogue: +bias, LN over 64 feats, residual (from LDS) + ReLU ----
    float cbv[4], lgv[4], lbv[4], whv[4];
    #pragma unroll
    for (int ft = 0; ft < 4; ++ft) {
        int j = ft * 16 + lrow;
        cbv[ft] = cb[j]; lgv[ft] = lg[j]; lbv[ft] = lb[j];
        if (LAST) whv[ft] = w_head[j];
    }
    float bh = LAST ? b_head[0] : 0.f;

    #pragma unroll
    for (int nt = 0; nt < 2; ++nt) {
        #pragma unroll
        for (int t = 0; t < 4; ++t) {
            int colc = cbase + nt * 16 + 4 * kgrp + t;   // grid column of this C-row
            int nl   = lr * 64 + colc;                   // block-local node
            float v[4], s1v = 0.f, s2v = 0.f;
            #pragma unroll
            for (int ft = 0; ft < 4; ++ft) {
                float xv = acc[nt][ft][t] + cbv[ft];
                v[ft] = xv; s1v += xv; s2v += xv * xv;
            }
            #pragma unroll
            for (int m = 1; m < 16; m <<= 1) {
                s1v += __shfl_xor(s1v, m);
                s2v += __shfl_xor(s2v, m);
            }
            float mu   = s1v * (1.0f / H);
            float var  = s2v * (1.0f / H) - mu * mu;
            float rstd = rsqrtf(var + LN_EPS);
            const _Float16* res = st + ((lr * 64 + colc) << 6);
            int cs = colc & 7;
            if (LAST) {
                float part = 0.f;
                #pragma unroll
                for (int ft = 0; ft < 4; ++ft) {
                    int j = ft * 16 + lrow;
                    float sv = (float)res[(((j >> 3) ^ cs) << 3) | (j & 7)];
                    float o  = sv + fmaxf((v[ft] - mu) * rstd * lgv[ft] + lbv[ft], 0.f);
                    part += o * whv[ft];
                }
                #pragma unroll
                for (int m = 1; m < 16; m <<= 1) part += __shfl_xor(part, m);
                if (lrow == 0) logits[(size_t)img * NN + nb + nl] = part + bh;
            } else {
                #pragma unroll
                for (int ft = 0; ft < 4; ++ft) {
                    int j = ft * 16 + lrow;
                    float sv = (float)res[(((j >> 3) ^ cs) << 3) | (j & 7)];
                    float o  = sv + fmaxf((v[ft] - mu) * rstd * lgv[ft] + lbv[ft], 0.f);
                    ho[(((size_t)(nb + nl)) << 6) + j] = (_Float16)o;
                }
            }
        }
    }
}

// ---------------------------------------------------------------------------
extern "C" void kernel_launch(void* const* d_in, const int* in_sizes, int n_in,
                              void* d_out, int out_size, void* d_ws, size_t ws_size,
                              hipStream_t stream) {
    const float* x      = (const float*)d_in[0];
    // d_in[1] edge_index: fixed grid 4-neighborhood -> computed as stencil, unused
    const float* w_in   = (const float*)d_in[2];
    const float* b_in   = (const float*)d_in[3];
    const float* w_self = (const float*)d_in[4];
    const float* w_neigh= (const float*)d_in[5];
    const float* conv_b = (const float*)d_in[6];
    const float* ln_g   = (const float*)d_in[7];
    const float* ln_b   = (const float*)d_in[8];
    const float* w_head = (const float*)d_in[9];
    const float* b_head = (const float*)d_in[10];
    float* out = (float*)d_out;

    char* base = (char*)d_ws;
    const size_t HBYTES = (size_t)B_SZ * NN * H * sizeof(_Float16);   // 64 MiB
    _Float16* h_a = (_Float16*)base;
    _Float16* h_b = (_Float16*)(base + HBYTES);
    _Float16* wtb = (_Float16*)(base + 2 * HBYTES);                   // 48 KiB

    k_prep<<<96, 256, 0, stream>>>(w_self, w_neigh, wtb);
    k_inproj<<<B_SZ * GRID_D, 256, 0, stream>>>(x, w_in, b_in, h_a);

    k_layer<false><<<B_SZ * 16, 512, 0, stream>>>(
        h_a, h_b, out, wtb,         conv_b,         ln_g,         ln_b,         w_head, b_head);
    k_layer<false><<<B_SZ * 16, 512, 0, stream>>>(
        h_b, h_a, out, wtb + 8192,  conv_b + H,     ln_g + H,     ln_b + H,     w_head, b_head);
    k_layer<true><<<B_SZ * 16, 512, 0, stream>>>(
        h_a, h_b, out, wtb + 16384, conv_b + 2 * H, ln_g + 2 * H, ln_b + 2 * H, w_head, b_head);
}

// Round 7
// 149.307 us; speedup vs baseline: 1.6453x; 1.1461x over previous
//
#include <hip/hip_runtime.h>

#define GRID_D 64
#define NN (GRID_D * GRID_D)   // 4096 nodes per image
#define H 64
#define C_IN 12
#define B_SZ 128
#define LN_EPS 1e-5f

typedef _Float16 f16x8 __attribute__((ext_vector_type(8)));
typedef _Float16 f16x4 __attribute__((ext_vector_type(4)));
typedef float    f32x4 __attribute__((ext_vector_type(4)));

#define AS1 __attribute__((address_space(1)))
#define AS3 __attribute__((address_space(3)))

// masked global halo-row read (grow is wave-uniform; OOB -> zero)
__device__ __forceinline__ f16x8 gload_row(const _Float16* hb, int grow, int col, int k0) {
    if ((unsigned)grow < (unsigned)GRID_D)
        return *(const f16x8*)(hb + (((size_t)(grow * GRID_D + col)) << 6) + k0);
    return (f16x8){};
}

// ---------------------------------------------------------------------------
// Kernel 0: weight prep — pre-swizzled transposed f16 copies of Ws/Wn.
// Layout: wt[l][g][j][slot][e] where slot = (k>>3)^(j&7), e = k&7, value W[k][j].
// ---------------------------------------------------------------------------
__global__ __launch_bounds__(256) void k_prep(
    const float* __restrict__ ws_, const float* __restrict__ wn_,
    _Float16* __restrict__ wt)
{
    int i = blockIdx.x * 256 + threadIdx.x;      // 0..24575
    if (i < 3 * 2 * 4096) {
        int l = i >> 13, g = (i >> 12) & 1, j = (i >> 6) & 63, k = i & 63;
        const float* W = (g ? wn_ : ws_) + l * 4096;
        int dst = (((l * 2 + g) * 64 + j) << 6) + ((((k >> 3) ^ (j & 7)) << 3) | (k & 7));
        wt[dst] = (_Float16)W[k * 64 + j];
    }
}

// ---------------------------------------------------------------------------
// Kernel 1: input projection  h[b,n,j] = sum_c x[b,c,n] * w_in[c,j] + b_in[j]
// 256 threads per grid row; thread = (node, 16-feat group); 16B stores.
// ---------------------------------------------------------------------------
__global__ __launch_bounds__(256) void k_inproj(
    const float* __restrict__ x, const float* __restrict__ w_in,
    const float* __restrict__ b_in, _Float16* __restrict__ h)
{
    int bid = blockIdx.x;            // b*64 + r
    int b = bid >> 6, r = bid & 63;
    __shared__ float xs[C_IN][GRID_D];
    __shared__ float ws[C_IN][H];
    int tid = threadIdx.x;
    const float* xb = x + (size_t)b * C_IN * NN + (size_t)r * GRID_D;
    for (int idx = tid; idx < C_IN * GRID_D; idx += 256) {
        int c = idx >> 6, n = idx & 63;
        xs[c][n] = xb[(size_t)c * NN + n];
        ws[c][n] = w_in[idx];
    }
    __syncthreads();
    int n = tid >> 2;                // node 0..63
    int j0 = (tid & 3) * 16;         // 16-feat group
    float acc[16];
    #pragma unroll
    for (int t = 0; t < 16; ++t) acc[t] = b_in[j0 + t];
    #pragma unroll
    for (int c = 0; c < C_IN; ++c) {
        float xv = xs[c][n];
        #pragma unroll
        for (int t = 0; t < 16; ++t) acc[t] += xv * ws[c][j0 + t];
    }
    _Float16* hp = h + (size_t)(b * NN + r * GRID_D + n) * H + j0;
    f16x8 o0, o1;
    #pragma unroll
    for (int t = 0; t < 8; ++t) { o0[t] = (_Float16)acc[t]; o1[t] = (_Float16)acc[8 + t]; }
    *(f16x8*)hp = o0;
    *(f16x8*)(hp + 8) = o1;
}

// ---------------------------------------------------------------------------
// Kernel 2: one SAGE layer + LayerNorm + residual ReLU (f16 state, MFMA).
// Block = 512 threads (8 waves) = 4 full grid rows (256 nodes) of one image.
// OPERAND-SWAPPED MFMA: C^T = W^T x h^T -> each lane owns 2 whole nodes
// (col=lane&15) x 16 j (reg dim). LN reduce = 2 shfl steps; 8B vector
// stores/residual reads. Params (cb/lg/lb/wh) in 1KB LDS.
// LDS 49KB -> 3 blocks/CU. LAST fuses the head.
// ---------------------------------------------------------------------------
template <bool LAST>
__global__ __launch_bounds__(512, 6) void k_layer(
    const _Float16* __restrict__ h_in, _Float16* __restrict__ h_out,
    float* __restrict__ logits,
    const _Float16* __restrict__ wtb,      // this layer's [2][64][64] pre-swizzled
    const float* __restrict__ cb, const float* __restrict__ lg,
    const float* __restrict__ lb,
    const float* __restrict__ w_head, const float* __restrict__ b_head)
{
    __shared__ _Float16 st[4 * 64 * 64];   // 32 KB tile
    __shared__ _Float16 wl[2 * 64 * 64];   // 16 KB weights
    __shared__ float    pl[256];           // 1 KB params: cb|lg|lb|wh

    int tid = threadIdx.x;
    int bid = blockIdx.x;                  // img*16 + tile
    int img = bid >> 4, tile = bid & 15;
    int r0 = tile * 4;
    const _Float16* hb = h_in + (size_t)img * NN * H;
    _Float16*       ho = h_out + (size_t)img * NN * H;
    int nb = r0 * GRID_D;

    int ln = tid & 63, wv = tid >> 6;
    int lnode = ln >> 3;                         // node within 8-node chunk
    int lslot = ((ln & 7) ^ lnode) << 3;         // pre-swizzled feat slot (elems)

    // ---- stage tile: rows r0..r0+3, 32 chunks of 1KB, 4 per wave ----
    #pragma unroll
    for (int i = 0; i < 4; ++i) {
        int q = i * 8 + wv;                      // 0..31
        int rr = q >> 3, cc0 = (q & 7) * 8;
        const _Float16* src = hb + (((size_t)((r0 + rr) * GRID_D + cc0 + lnode)) << 6) + lslot;
        _Float16* dst = st + ((size_t)(rr * 64 + cc0) << 6);
        __builtin_amdgcn_global_load_lds((const AS1 void*)src, (AS3 void*)dst, 16, 0, 0);
    }
    // ---- stage weights: 16 chunks of 1KB, linear both sides ----
    #pragma unroll
    for (int i = 0; i < 2; ++i) {
        int c = i * 8 + wv;                      // 0..15
        const _Float16* src = wtb + c * 512 + ln * 8;
        _Float16* dst = wl + c * 512;
        __builtin_amdgcn_global_load_lds((const AS1 void*)src, (AS3 void*)dst, 16, 0, 0);
    }
    // ---- stage params ----
    if (tid < 256) {
        float v = (tid < 64) ? cb[tid]
                : (tid < 128) ? lg[tid - 64]
                : (tid < 192) ? lb[tid - 128] : w_head[tid - 192];
        pl[tid] = v;
    }
    __syncthreads();   // drains vmcnt before barrier

    // ---- GEMM setup ----
    int lrow = ln & 15, kgrp = ln >> 4;
    int lr = wv >> 1;                     // wave's tile-local row 0..3
    int cbase = (wv & 1) * 32;
    int col0 = cbase + lrow;              // node-tile-0 column (0..47)
    int col1 = cbase + 16 + lrow;         // node-tile-1 column (16..63)
    int growc = r0 + lr;                  // global grid row

    f32x4 acc[2][4];                      // [node-tile nt][j-tile ft], C^T frags
    #pragma unroll
    for (int nt = 0; nt < 2; ++nt)
        #pragma unroll
        for (int ft = 0; ft < 4; ++ft) acc[nt][ft] = (f32x4){0.f, 0.f, 0.f, 0.f};

    // ---- phase 1: Ws^T @ self^T ----
    #pragma unroll
    for (int ks = 0; ks < 2; ++ks) {
        int c8 = ks * 4 + kgrp;
        int sl = (c8 ^ (lrow & 7)) << 3;
        f16x8 a0 = *(const f16x8*)(st + ((lr * 64 + col0) << 6) + sl);
        f16x8 a1 = *(const f16x8*)(st + ((lr * 64 + col1) << 6) + sl);
        #pragma unroll
        for (int ft = 0; ft < 4; ++ft) {
            int j = ft * 16 + lrow;
            f16x8 wf = *(const f16x8*)(wl + (j << 6) + sl);
            acc[0][ft] = __builtin_amdgcn_mfma_f32_16x16x32_f16(wf, a0, acc[0][ft], 0, 0, 0);
            acc[1][ft] = __builtin_amdgcn_mfma_f32_16x16x32_f16(wf, a1, acc[1][ft], 0, 0, 0);
        }
    }

    // ---- phase 2: Wn^T @ agg^T (neighbor mean built with packed f16 adds) ----
    _Float16 inv0 = (_Float16)(1.0f / (float)((growc > 0) + (growc < 63) + (col0 > 0) + 1));
    _Float16 inv1 = (_Float16)(1.0f / (float)((growc > 0) + (growc < 63) + 1 + (col1 < 63)));
    #pragma unroll
    for (int ks = 0; ks < 2; ++ks) {
        int c8 = ks * 4 + kgrp;
        int sl = (c8 ^ (lrow & 7)) << 3;
        int k0 = ks * 32 + kgrp * 8;
        f16x8 z = {};

        // --- node tile 0 ---
        f16x8 u0 = (lr > 0) ? *(const f16x8*)(st + (((lr - 1) * 64 + col0) << 6) + sl)
                            : gload_row(hb, r0 - 1, col0, k0);
        f16x8 d0 = (lr < 3) ? *(const f16x8*)(st + (((lr + 1) * 64 + col0) << 6) + sl)
                            : gload_row(hb, r0 + 4, col0, k0);
        int cm0 = col0 - (col0 > 0);
        f16x8 l0 = *(const f16x8*)(st + ((lr * 64 + cm0) << 6) + ((c8 ^ (cm0 & 7)) << 3));
        if (col0 == 0) l0 = z;
        int cp0 = col0 + 1;                                   // <= 48, always in tile
        f16x8 r0v = *(const f16x8*)(st + ((lr * 64 + cp0) << 6) + ((c8 ^ (cp0 & 7)) << 3));
        f16x8 s0 = (l0 + r0v) + (u0 + d0);
        f16x8 g0;
        #pragma unroll
        for (int e = 0; e < 8; ++e) g0[e] = s0[e] * inv0;

        // --- node tile 1 ---
        f16x8 u1 = (lr > 0) ? *(const f16x8*)(st + (((lr - 1) * 64 + col1) << 6) + sl)
                            : gload_row(hb, r0 - 1, col1, k0);
        f16x8 d1 = (lr < 3) ? *(const f16x8*)(st + (((lr + 1) * 64 + col1) << 6) + sl)
                            : gload_row(hb, r0 + 4, col1, k0);
        int cm1 = col1 - 1;                                   // >= 15, always in tile
        f16x8 l1 = *(const f16x8*)(st + ((lr * 64 + cm1) << 6) + ((c8 ^ (cm1 & 7)) << 3));
        int cp1 = col1 + (col1 < 63);
        f16x8 r1v = *(const f16x8*)(st + ((lr * 64 + cp1) << 6) + ((c8 ^ (cp1 & 7)) << 3));
        if (col1 == 63) r1v = z;
        f16x8 s1x = (l1 + r1v) + (u1 + d1);
        f16x8 g1;
        #pragma unroll
        for (int e = 0; e < 8; ++e) g1[e] = s1x[e] * inv1;

        #pragma unroll
        for (int ft = 0; ft < 4; ++ft) {
            int j = ft * 16 + lrow;
            f16x8 wf = *(const f16x8*)(wl + ((64 + j) << 6) + sl);
            acc[0][ft] = __builtin_amdgcn_mfma_f32_16x16x32_f16(wf, g0, acc[0][ft], 0, 0, 0);
            acc[1][ft] = __builtin_amdgcn_mfma_f32_16x16x32_f16(wf, g1, acc[1][ft], 0, 0, 0);
        }
    }

    // ---- epilogue (C^T layout: lane owns node col, 16 j across ft/reg) ----
    int kq = kgrp * 4;                    // j-quad base within a 16-block
    // add conv bias in place
    #pragma unroll
    for (int ft = 0; ft < 4; ++ft) {
        f32x4 q = *(const f32x4*)&pl[ft * 16 + kq];
        acc[0][ft] += q;
        acc[1][ft] += q;
    }
    float bh = LAST ? b_head[0] : 0.f;

    #pragma unroll
    for (int nt = 0; nt < 2; ++nt) {
        int colc = cbase + nt * 16 + lrow;       // this lane's node column
        int node = lr * 64 + colc;               // block-local node
        float s1 = 0.f, s2 = 0.f;
        #pragma unroll
        for (int ft = 0; ft < 4; ++ft)
            #pragma unroll
            for (int t = 0; t < 4; ++t) {
                float xv = acc[nt][ft][t];
                s1 += xv; s2 += xv * xv;
            }
        // reduce across the 4 kgrp groups holding this node's other j-quads
        s1 += __shfl_xor(s1, 16); s1 += __shfl_xor(s1, 32);
        s2 += __shfl_xor(s2, 16); s2 += __shfl_xor(s2, 32);
        float mu   = s1 * (1.0f / H);
        float var  = s2 * (1.0f / H) - mu * mu;
        float rstd = rsqrtf(var + LN_EPS);

        const _Float16* resrow = st + ((lr * 64 + colc) << 6);
        int cs = colc & 7;
        float part = 0.f;
        #pragma unroll
        for (int ft = 0; ft < 4; ++ft) {
            f32x4 lgq = *(const f32x4*)&pl[64 + ft * 16 + kq];
            f32x4 lbq = *(const f32x4*)&pl[128 + ft * 16 + kq];
            int slot = (ft * 2 + (kgrp >> 1)) ^ cs;
            f16x4 rq = *(const f16x4*)(resrow + (slot << 3) + (kgrp & 1) * 4);
            if (LAST) {
                f32x4 whq = *(const f32x4*)&pl[192 + ft * 16 + kq];
                #pragma unroll
                for (int t = 0; t < 4; ++t) {
                    float o = (float)rq[t]
                            + fmaxf((acc[nt][ft][t] - mu) * rstd * lgq[t] + lbq[t], 0.f);
                    part += o * whq[t];
                }
            } else {
                f16x4 oq;
                #pragma unroll
                for (int t = 0; t < 4; ++t) {
                    float o = (float)rq[t]
                            + fmaxf((acc[nt][ft][t] - mu) * rstd * lgq[t] + lbq[t], 0.f);
                    oq[t] = (_Float16)o;
                }
                *(f16x4*)(ho + (((size_t)(nb + node)) << 6) + ft * 16 + kq) = oq;
            }
        }
        if (LAST) {
            part += __shfl_xor(part, 16);
            part += __shfl_xor(part, 32);
            if (kgrp == 0) logits[(size_t)img * NN + nb + node] = part + bh;
        }
    }
}

// ---------------------------------------------------------------------------
extern "C" void kernel_launch(void* const* d_in, const int* in_sizes, int n_in,
                              void* d_out, int out_size, void* d_ws, size_t ws_size,
                              hipStream_t stream) {
    const float* x      = (const float*)d_in[0];
    // d_in[1] edge_index: fixed grid 4-neighborhood -> computed as stencil, unused
    const float* w_in   = (const float*)d_in[2];
    const float* b_in   = (const float*)d_in[3];
    const float* w_self = (const float*)d_in[4];
    const float* w_neigh= (const float*)d_in[5];
    const float* conv_b = (const float*)d_in[6];
    const float* ln_g   = (const float*)d_in[7];
    const float* ln_b   = (const float*)d_in[8];
    const float* w_head = (const float*)d_in[9];
    const float* b_head = (const float*)d_in[10];
    float* out = (float*)d_out;

    char* base = (char*)d_ws;
    const size_t HBYTES = (size_t)B_SZ * NN * H * sizeof(_Float16);   // 64 MiB
    _Float16* h_a = (_Float16*)base;
    _Float16* h_b = (_Float16*)(base + HBYTES);
    _Float16* wtb = (_Float16*)(base + 2 * HBYTES);                   // 48 KiB

    k_prep<<<96, 256, 0, stream>>>(w_self, w_neigh, wtb);
    k_inproj<<<B_SZ * GRID_D, 256, 0, stream>>>(x, w_in, b_in, h_a);

    k_layer<false><<<B_SZ * 16, 512, 0, stream>>>(
        h_a, h_b, out, wtb,         conv_b,         ln_g,         ln_b,         w_head, b_head);
    k_layer<false><<<B_SZ * 16, 512, 0, stream>>>(
        h_b, h_a, out, wtb + 8192,  conv_b + H,     ln_g + H,     ln_b + H,     w_head, b_head);
    k_layer<true><<<B_SZ * 16, 512, 0, stream>>>(
        h_a, h_b, out, wtb + 16384, conv_b + 2 * H, ln_g + 2 * H, ln_b + 2 * H, w_head, b_head);
}

// Round 8
// 126.705 us; speedup vs baseline: 1.9389x; 1.1784x over previous
//
#include <hip/hip_runtime.h>

#define GRID_D 64
#define NN (GRID_D * GRID_D)   // 4096 nodes per image
#define H 64
#define C_IN 12
#define B_SZ 128
#define LN_EPS 1e-5f

typedef _Float16 f16x8 __attribute__((ext_vector_type(8)));
typedef _Float16 f16x4 __attribute__((ext_vector_type(4)));
typedef float    f32x4 __attribute__((ext_vector_type(4)));

#define AS1 __attribute__((address_space(1)))
#define AS3 __attribute__((address_space(3)))

// LDS layout (dynamic): ring[6][4096] f16 | wl[8192] f16 | pl[256] f32
#define RING_ELEMS (6 * 4096)
#define WL_ELEMS   (2 * 64 * 64)
#define SMEM_BYTES ((RING_ELEMS + WL_ELEMS) * 2 + 256 * 4)   // 66,560 B

// ---------------------------------------------------------------------------
// Kernel 0: weight prep — pre-swizzled transposed f16 copies of Ws/Wn.
// wt[l][g][j][slot][e]: slot = (k>>3)^(j&7), e = k&7, value W[k][j].
// ---------------------------------------------------------------------------
__global__ __launch_bounds__(256) void k_prep(
    const float* __restrict__ ws_, const float* __restrict__ wn_,
    _Float16* __restrict__ wt)
{
    int i = blockIdx.x * 256 + threadIdx.x;      // 0..24575
    if (i < 3 * 2 * 4096) {
        int l = i >> 13, g = (i >> 12) & 1, j = (i >> 6) & 63, k = i & 63;
        const float* W = (g ? wn_ : ws_) + l * 4096;
        int dst = (((l * 2 + g) * 64 + j) << 6) + ((((k >> 3) ^ (j & 7)) << 3) | (k & 7));
        wt[dst] = (_Float16)W[k * 64 + j];
    }
}

// ---------------------------------------------------------------------------
// Kernel 1: input projection  h[b,n,j] = sum_c x[b,c,n] * w_in[c,j] + b_in[j]
// ---------------------------------------------------------------------------
__global__ __launch_bounds__(256) void k_inproj(
    const float* __restrict__ x, const float* __restrict__ w_in,
    const float* __restrict__ b_in, _Float16* __restrict__ h)
{
    int bid = blockIdx.x;            // b*64 + r
    int b = bid >> 6, r = bid & 63;
    __shared__ float xs[C_IN][GRID_D];
    __shared__ float ws[C_IN][H];
    int tid = threadIdx.x;
    const float* xb = x + (size_t)b * C_IN * NN + (size_t)r * GRID_D;
    for (int idx = tid; idx < C_IN * GRID_D; idx += 256) {
        int c = idx >> 6, n = idx & 63;
        xs[c][n] = xb[(size_t)c * NN + n];
        ws[c][n] = w_in[idx];
    }
    __syncthreads();
    int n = tid >> 2;                // node 0..63
    int j0 = (tid & 3) * 16;         // 16-feat group
    float acc[16];
    #pragma unroll
    for (int t = 0; t < 16; ++t) acc[t] = b_in[j0 + t];
    #pragma unroll
    for (int c = 0; c < C_IN; ++c) {
        float xv = xs[c][n];
        #pragma unroll
        for (int t = 0; t < 16; ++t) acc[t] += xv * ws[c][j0 + t];
    }
    _Float16* hp = h + (size_t)(b * NN + r * GRID_D + n) * H + j0;
    f16x8 o0, o1;
    #pragma unroll
    for (int t = 0; t < 8; ++t) { o0[t] = (_Float16)acc[t]; o1[t] = (_Float16)acc[8 + t]; }
    *(f16x8*)hp = o0;
    *(f16x8*)(hp + 8) = o1;
}

// stage one grid row (64 nodes x 64 f16 = 8KB) into a ring slot; linear dest,
// pre-swizzled per-lane global source (rule 21). One gload_lds per wave call.
__device__ __forceinline__ void stage_row(
    const _Float16* hb, int grow, int slotbase, int wv, int ln, _Float16* ring)
{
    const _Float16* src = hb
        + (((size_t)(grow * GRID_D + wv * 8 + (ln >> 3))) << 6)
        + (((ln & 7) ^ (ln >> 3)) << 3);
    _Float16* dst = ring + slotbase + wv * 512;
    __builtin_amdgcn_global_load_lds((const AS1 void*)src, (AS3 void*)dst, 16, 0, 0);
}

// ---------------------------------------------------------------------------
// Kernel 2: one SAGE layer + LayerNorm + residual ReLU (f16, MFMA, operand-
// swapped). PERSISTENT MARCH: block = 512 thr (8 waves) owns 16 grid rows of
// one image, marches in 2-row steps. 6-slot row ring in LDS: compute rows
// {r,r+1} (slots r-1..r+2) while prefetching rows r+3,r+4 into the free
// slots; end-of-step barrier lands the prefetch. Weights staged once/block.
// Wave wv: row r+(wv>>2), col tile (wv&3)*16. LAST fuses the head.
// ---------------------------------------------------------------------------
template <bool LAST>
__global__ __launch_bounds__(512, 4) void k_layer(
    const _Float16* __restrict__ h_in, _Float16* __restrict__ h_out,
    float* __restrict__ logits,
    const _Float16* __restrict__ wtb,      // this layer's [2][64][64] pre-swizzled
    const float* __restrict__ cb, const float* __restrict__ lg,
    const float* __restrict__ lb,
    const float* __restrict__ w_head, const float* __restrict__ b_head)
{
    extern __shared__ _Float16 smem[];
    _Float16* ring = smem;                     // 6 x 4096 f16 (48 KB)
    _Float16* wl   = smem + RING_ELEMS;        // 8192 f16 (16 KB)
    float*    pl   = (float*)(smem + RING_ELEMS + WL_ELEMS);   // 256 f32

    int tid = threadIdx.x, ln = tid & 63, wv = tid >> 6;
    int bid = blockIdx.x;                      // img*4 + chunk
    int img = bid >> 2, chunk = bid & 3;
    int r0 = chunk << 4;                       // first compute row of chunk
    const _Float16* hb = h_in + ((size_t)img << 18);
    _Float16*       ho = h_out + ((size_t)img << 18);

    // ---- prologue: stage rows r0-1..r0+2, weights, params ----
    #pragma unroll
    for (int i = 0; i < 4; ++i) {
        int grow = r0 - 1 + i;
        if (grow >= 0)                         // block-uniform branch
            stage_row(hb, grow, ((grow + 1) % 6) * 4096, wv, ln, ring);
    }
    #pragma unroll
    for (int i = 0; i < 2; ++i) {
        const _Float16* src = wtb + i * 4096 + (wv * 64 + ln) * 8;
        _Float16* dst = wl + i * 4096 + wv * 512;
        __builtin_amdgcn_global_load_lds((const AS1 void*)src, (AS3 void*)dst, 16, 0, 0);
    }
    if (tid < 256) {
        float v = (tid < 64) ? cb[tid]
                : (tid < 128) ? lg[tid - 64]
                : (tid < 192) ? lb[tid - 128] : w_head[tid - 192];
        pl[tid] = v;
    }
    __syncthreads();

    int lrow = ln & 15, kgrp = ln >> 4;
    int colb = (wv & 3) * 16;
    int col  = colb + lrow;                    // this lane's grid column
    int wr   = wv >> 2;                        // 0 or 1: which row of the pair
    int kq   = kgrp * 4;
    int cs   = lrow & 7;                       // col & 7
    bool cl = (col > 0), cr = (col < 63);
    float bh = LAST ? b_head[0] : 0.f;

    for (int step = 0; step < 8; ++step) {
        int r = r0 + 2 * step;
        // ---- prefetch next 2 rows into the free slots ----
        if (step < 7) {
            int p0 = r + 3;
            stage_row(hb, p0, ((p0 + 1) % 6) * 4096, wv, ln, ring);
            int p1 = r + 4;
            if (p1 < GRID_D)
                stage_row(hb, p1, ((p1 + 1) % 6) * 4096, wv, ln, ring);
        }

        int rw = r + wr;                       // this wave's grid row
        const _Float16* rc = ring + ((rw + 1) % 6) * 4096;   // row rw
        const _Float16* ru = ring + ((rw)     % 6) * 4096;   // row rw-1
        const _Float16* rd = ring + ((rw + 2) % 6) * 4096;   // row rw+1
        _Float16 hinv = (_Float16)(1.0f / (float)((rw > 0) + (rw < 63) + cl + cr));

        f32x4 acc[4];
        #pragma unroll
        for (int ft = 0; ft < 4; ++ft) acc[ft] = (f32x4){0.f, 0.f, 0.f, 0.f};

        // ---- phase 1: Ws^T @ self^T ----
        #pragma unroll
        for (int ks = 0; ks < 2; ++ks) {
            int c8 = ks * 4 + kgrp;
            int sl = (c8 ^ cs) << 3;
            f16x8 a = *(const f16x8*)(rc + (col << 6) + sl);
            #pragma unroll
            for (int ft = 0; ft < 4; ++ft) {
                f16x8 wf = *(const f16x8*)(wl + ((ft * 16 + lrow) << 6) + sl);
                acc[ft] = __builtin_amdgcn_mfma_f32_16x16x32_f16(wf, a, acc[ft], 0, 0, 0);
            }
        }

        // ---- phase 2: Wn^T @ agg^T ----
        #pragma unroll
        for (int ks = 0; ks < 2; ++ks) {
            int c8 = ks * 4 + kgrp;
            int sl = (c8 ^ cs) << 3;
            f16x8 z = {};
            f16x8 u = (rw > 0)          ? *(const f16x8*)(ru + (col << 6) + sl) : z;
            f16x8 d = (rw < GRID_D - 1) ? *(const f16x8*)(rd + (col << 6) + sl) : z;
            int cm = col - cl;
            f16x8 lv = *(const f16x8*)(rc + (cm << 6) + ((c8 ^ (cm & 7)) << 3));
            if (!cl) lv = z;
            int cp = col + cr;
            f16x8 rv = *(const f16x8*)(rc + (cp << 6) + ((c8 ^ (cp & 7)) << 3));
            if (!cr) rv = z;
            f16x8 s = (lv + rv) + (u + d);
            f16x8 g;
            #pragma unroll
            for (int e = 0; e < 8; ++e) g[e] = s[e] * hinv;
            #pragma unroll
            for (int ft = 0; ft < 4; ++ft) {
                f16x8 wf = *(const f16x8*)(wl + ((64 + ft * 16 + lrow) << 6) + sl);
                acc[ft] = __builtin_amdgcn_mfma_f32_16x16x32_f16(wf, g, acc[ft], 0, 0, 0);
            }
        }

        // ---- epilogue: +bias, LN, residual+ReLU, store (or head) ----
        float s1 = 0.f, s2 = 0.f;
        #pragma unroll
        for (int ft = 0; ft < 4; ++ft) {
            f32x4 q = *(const f32x4*)&pl[ft * 16 + kq];
            acc[ft] += q;
            #pragma unroll
            for (int t = 0; t < 4; ++t) { float xv = acc[ft][t]; s1 += xv; s2 += xv * xv; }
        }
        s1 += __shfl_xor(s1, 16); s1 += __shfl_xor(s1, 32);
        s2 += __shfl_xor(s2, 16); s2 += __shfl_xor(s2, 32);
        float mu   = s1 * (1.0f / H);
        float var  = s2 * (1.0f / H) - mu * mu;
        float rstd = rsqrtf(var + LN_EPS);

        const _Float16* res = rc + (col << 6);
        float part = 0.f;
        #pragma unroll
        for (int ft = 0; ft < 4; ++ft) {
            f32x4 lgq = *(const f32x4*)&pl[64 + ft * 16 + kq];
            f32x4 lbq = *(const f32x4*)&pl[128 + ft * 16 + kq];
            int slot = (ft * 2 + (kgrp >> 1)) ^ cs;
            f16x4 rq = *(const f16x4*)(res + (slot << 3) + (kgrp & 1) * 4);
            if (LAST) {
                f32x4 whq = *(const f32x4*)&pl[192 + ft * 16 + kq];
                #pragma unroll
                for (int t = 0; t < 4; ++t) {
                    float o = (float)rq[t]
                            + fmaxf((acc[ft][t] - mu) * rstd * lgq[t] + lbq[t], 0.f);
                    part += o * whq[t];
                }
            } else {
                f16x4 oq;
                #pragma unroll
                for (int t = 0; t < 4; ++t) {
                    float o = (float)rq[t]
                            + fmaxf((acc[ft][t] - mu) * rstd * lgq[t] + lbq[t], 0.f);
                    oq[t] = (_Float16)o;
                }
                *(f16x4*)(ho + (((size_t)(rw * GRID_D + col)) << 6) + ft * 16 + kq) = oq;
            }
        }
        if (LAST) {
            part += __shfl_xor(part, 16);
            part += __shfl_xor(part, 32);
            if (kgrp == 0) logits[(size_t)img * NN + rw * GRID_D + col] = part + bh;
        }

        __syncthreads();   // lands prefetch (vmcnt drain) + protects slot reuse
    }
}

// ---------------------------------------------------------------------------
extern "C" void kernel_launch(void* const* d_in, const int* in_sizes, int n_in,
                              void* d_out, int out_size, void* d_ws, size_t ws_size,
                              hipStream_t stream) {
    const float* x      = (const float*)d_in[0];
    // d_in[1] edge_index: fixed grid 4-neighborhood -> computed as stencil, unused
    const float* w_in   = (const float*)d_in[2];
    const float* b_in   = (const float*)d_in[3];
    const float* w_self = (const float*)d_in[4];
    const float* w_neigh= (const float*)d_in[5];
    const float* conv_b = (const float*)d_in[6];
    const float* ln_g   = (const float*)d_in[7];
    const float* ln_b   = (const float*)d_in[8];
    const float* w_head = (const float*)d_in[9];
    const float* b_head = (const float*)d_in[10];
    float* out = (float*)d_out;

    char* base = (char*)d_ws;
    const size_t HBYTES = (size_t)B_SZ * NN * H * sizeof(_Float16);   // 64 MiB
    _Float16* h_a = (_Float16*)base;
    _Float16* h_b = (_Float16*)(base + HBYTES);
    _Float16* wtb = (_Float16*)(base + 2 * HBYTES);                   // 48 KiB

    (void)hipFuncSetAttribute(reinterpret_cast<const void*>(&k_layer<false>),
                              hipFuncAttributeMaxDynamicSharedMemorySize, SMEM_BYTES);
    (void)hipFuncSetAttribute(reinterpret_cast<const void*>(&k_layer<true>),
                              hipFuncAttributeMaxDynamicSharedMemorySize, SMEM_BYTES);

    k_prep<<<96, 256, 0, stream>>>(w_self, w_neigh, wtb);
    k_inproj<<<B_SZ * GRID_D, 256, 0, stream>>>(x, w_in, b_in, h_a);

    k_layer<false><<<B_SZ * 4, 512, SMEM_BYTES, stream>>>(
        h_a, h_b, out, wtb,         conv_b,         ln_g,         ln_b,         w_head, b_head);
    k_layer<false><<<B_SZ * 4, 512, SMEM_BYTES, stream>>>(
        h_b, h_a, out, wtb + 8192,  conv_b + H,     ln_g + H,     ln_b + H,     w_head, b_head);
    k_layer<true><<<B_SZ * 4, 512, SMEM_BYTES, stream>>>(
        h_a, h_b, out, wtb + 16384, conv_b + 2 * H, ln_g + 2 * H, ln_b + 2 * H, w_head, b_head);
}